// Round 1
// baseline (17715.633 us; speedup 1.0000x reference)
//
#include <hip/hip_runtime.h>
#include <hip/hip_bf16.h>
#include <math.h>

// Whisper decoder forward, fp32 baseline.
// L=12 B=4 T=448 S=1500 D=768 NH=12 DH=64 V=51865 DFF=3072
#define NL   12
#define NB   4
#define NT   448
#define NS   1500
#define ND   768
#define NHD  12
#define NDH  64
#define NV   51865
#define NDFF 3072
#define NR   (NB * NT)   // 1792 rows

__device__ __forceinline__ float gelu_f(float x) {
    return 0.5f * x * (1.f + erff(x * 0.7071067811865476f));
}

// ---------------------------------------------------------------- embed
__global__ __launch_bounds__(256)
void k_embed(const int* __restrict__ tokens, const float* __restrict__ tok_emb,
             const float* __restrict__ pos_emb, float* __restrict__ x) {
    int row = blockIdx.x;            // 0..NR-1
    int t   = row % NT;
    int tok = tokens[row];
    const float* te = tok_emb + (size_t)tok * ND;
    const float* pe = pos_emb + (size_t)t * ND;
    float* xr = x + (size_t)row * ND;
    int c = threadIdx.x;
    xr[c]       = te[c]       + pe[c];
    xr[c + 256] = te[c + 256] + pe[c + 256];
    xr[c + 512] = te[c + 512] + pe[c + 512];
}

// ---------------------------------------------------------------- layernorm (row of 768, fp32)
__global__ __launch_bounds__(256)
void k_ln(const float* __restrict__ x, const float* __restrict__ g,
          const float* __restrict__ b, float* __restrict__ out) {
    __shared__ float red[8];
    int row = blockIdx.x;
    const float* xr = x + (size_t)row * ND;
    float* orow = out + (size_t)row * ND;
    int t = threadIdx.x;
    float a0 = xr[t], a1 = xr[t + 256], a2 = xr[t + 512];
    float s  = a0 + a1 + a2;
    float s2 = a0 * a0 + a1 * a1 + a2 * a2;
    #pragma unroll
    for (int off = 32; off > 0; off >>= 1) {
        s  += __shfl_down(s, off);
        s2 += __shfl_down(s2, off);
    }
    int w = t >> 6;
    if ((t & 63) == 0) { red[w * 2] = s; red[w * 2 + 1] = s2; }
    __syncthreads();
    s  = red[0] + red[2] + red[4] + red[6];
    s2 = red[1] + red[3] + red[5] + red[7];
    float mean = s * (1.f / ND);
    float var  = s2 * (1.f / ND) - mean * mean;
    float inv  = rsqrtf(var + 1e-5f);
    orow[t]       = (a0 - mean) * inv * g[t]       + b[t];
    orow[t + 256] = (a1 - mean) * inv * g[t + 256] + b[t + 256];
    orow[t + 512] = (a2 - mean) * inv * g[t + 512] + b[t + 512];
}

// ---------------------------------------------------------------- GEMM 64x64, BK=32, 4x4/thread
// out = [act?gelu](A@W + bias) + resid ; A: MxK, W: KxN row-major. M%64==0, N%64==0, K%32==0.
__global__ __launch_bounds__(256)
void k_gemm64(const float* __restrict__ A, const float* __restrict__ W,
              const float* __restrict__ bias, const float* __restrict__ resid,
              float* __restrict__ out, int M, int N, int K, int act) {
    __shared__ float As[32][68];
    __shared__ float Bs[32][68];
    const int tid = threadIdx.x;
    const int m0 = blockIdx.x * 64, n0 = blockIdx.y * 64;
    const int tx = tid & 15, ty = tid >> 4;
    const int ar = tid >> 3, ac4 = (tid & 7) * 4;
    const int br = tid >> 4, bc4 = (tid & 15) * 4;
    float acc[4][4] = {};
    for (int k0 = 0; k0 < K; k0 += 32) {
        float4 a0 = *(const float4*)&A[(size_t)(m0 + ar) * K + k0 + ac4];
        float4 a1 = *(const float4*)&A[(size_t)(m0 + ar + 32) * K + k0 + ac4];
        float4 b0 = *(const float4*)&W[(size_t)(k0 + br) * N + n0 + bc4];
        float4 b1 = *(const float4*)&W[(size_t)(k0 + br + 16) * N + n0 + bc4];
        __syncthreads();
        As[ac4 + 0][ar] = a0.x; As[ac4 + 1][ar] = a0.y;
        As[ac4 + 2][ar] = a0.z; As[ac4 + 3][ar] = a0.w;
        As[ac4 + 0][ar + 32] = a1.x; As[ac4 + 1][ar + 32] = a1.y;
        As[ac4 + 2][ar + 32] = a1.z; As[ac4 + 3][ar + 32] = a1.w;
        *(float4*)&Bs[br][bc4]      = b0;
        *(float4*)&Bs[br + 16][bc4] = b1;
        __syncthreads();
        #pragma unroll
        for (int kk = 0; kk < 32; ++kk) {
            float4 av = *(const float4*)&As[kk][ty * 4];
            float4 bv = *(const float4*)&Bs[kk][tx * 4];
            float a_[4] = {av.x, av.y, av.z, av.w};
            float b_[4] = {bv.x, bv.y, bv.z, bv.w};
            #pragma unroll
            for (int i = 0; i < 4; ++i)
                #pragma unroll
                for (int j = 0; j < 4; ++j)
                    acc[i][j] = fmaf(a_[i], b_[j], acc[i][j]);
        }
    }
    #pragma unroll
    for (int i = 0; i < 4; ++i) {
        int row = m0 + ty * 4 + i;
        int col = n0 + tx * 4;
        float vv[4];
        #pragma unroll
        for (int j = 0; j < 4; ++j) vv[j] = acc[i][j];
        if (bias) {
            #pragma unroll
            for (int j = 0; j < 4; ++j) vv[j] += bias[col + j];
        }
        if (act) {
            #pragma unroll
            for (int j = 0; j < 4; ++j) vv[j] = gelu_f(vv[j]);
        }
        if (resid) {
            #pragma unroll
            for (int j = 0; j < 4; ++j) vv[j] += resid[(size_t)row * N + col + j];
        }
        *(float4*)&out[(size_t)row * N + col] = make_float4(vv[0], vv[1], vv[2], vv[3]);
    }
}

// ---------------------------------------------------------------- GEMM 128x128, BK=16, 8x8/thread
// transB=0: W is KxN row-major (N%128==0). transB=1: W is NxK row-major (B^T), N ragged OK.
__global__ __launch_bounds__(256)
void k_gemm128(const float* __restrict__ A, const float* __restrict__ W,
               const float* __restrict__ bias, float* __restrict__ out,
               int M, int N, int K, int act, int transB) {
    __shared__ float As[16][132];
    __shared__ float Bs[16][132];
    const int tid = threadIdx.x;
    const int m0 = blockIdx.x * 128, n0 = blockIdx.y * 128;
    const int tx = tid & 15, ty = tid >> 4;
    const int ar = tid >> 2, ac4 = (tid & 3) * 4;
    const int brr = tid >> 5, bc4n = (tid & 31) * 4;
    float acc[2][2][4][4] = {};
    for (int k0 = 0; k0 < K; k0 += 16) {
        float4 a0 = *(const float4*)&A[(size_t)(m0 + ar) * K + k0 + ac4];
        float4 a1 = *(const float4*)&A[(size_t)(m0 + ar + 64) * K + k0 + ac4];
        float4 b0, b1;
        if (!transB) {
            b0 = *(const float4*)&W[(size_t)(k0 + brr) * N + n0 + bc4n];
            b1 = *(const float4*)&W[(size_t)(k0 + brr + 8) * N + n0 + bc4n];
        } else {
            int r0 = n0 + ar, r1 = n0 + ar + 64;
            b0 = (r0 < N) ? *(const float4*)&W[(size_t)r0 * K + k0 + ac4] : make_float4(0, 0, 0, 0);
            b1 = (r1 < N) ? *(const float4*)&W[(size_t)r1 * K + k0 + ac4] : make_float4(0, 0, 0, 0);
        }
        __syncthreads();
        As[ac4 + 0][ar] = a0.x; As[ac4 + 1][ar] = a0.y;
        As[ac4 + 2][ar] = a0.z; As[ac4 + 3][ar] = a0.w;
        As[ac4 + 0][ar + 64] = a1.x; As[ac4 + 1][ar + 64] = a1.y;
        As[ac4 + 2][ar + 64] = a1.z; As[ac4 + 3][ar + 64] = a1.w;
        if (!transB) {
            *(float4*)&Bs[brr][bc4n]     = b0;
            *(float4*)&Bs[brr + 8][bc4n] = b1;
        } else {
            Bs[ac4 + 0][ar] = b0.x; Bs[ac4 + 1][ar] = b0.y;
            Bs[ac4 + 2][ar] = b0.z; Bs[ac4 + 3][ar] = b0.w;
            Bs[ac4 + 0][ar + 64] = b1.x; Bs[ac4 + 1][ar + 64] = b1.y;
            Bs[ac4 + 2][ar + 64] = b1.z; Bs[ac4 + 3][ar + 64] = b1.w;
        }
        __syncthreads();
        #pragma unroll
        for (int kk = 0; kk < 16; ++kk) {
            float4 alv = *(const float4*)&As[kk][ty * 4];
            float4 ahv = *(const float4*)&As[kk][64 + ty * 4];
            float4 blv = *(const float4*)&Bs[kk][tx * 4];
            float4 bhv = *(const float4*)&Bs[kk][64 + tx * 4];
            float al[4] = {alv.x, alv.y, alv.z, alv.w};
            float ah[4] = {ahv.x, ahv.y, ahv.z, ahv.w};
            float bl[4] = {blv.x, blv.y, blv.z, blv.w};
            float bh[4] = {bhv.x, bhv.y, bhv.z, bhv.w};
            #pragma unroll
            for (int i = 0; i < 4; ++i)
                #pragma unroll
                for (int j = 0; j < 4; ++j) {
                    acc[0][0][i][j] = fmaf(al[i], bl[j], acc[0][0][i][j]);
                    acc[0][1][i][j] = fmaf(al[i], bh[j], acc[0][1][i][j]);
                    acc[1][0][i][j] = fmaf(ah[i], bl[j], acc[1][0][i][j]);
                    acc[1][1][i][j] = fmaf(ah[i], bh[j], acc[1][1][i][j]);
                }
        }
    }
    #pragma unroll
    for (int rh = 0; rh < 2; ++rh)
        #pragma unroll
        for (int i = 0; i < 4; ++i) {
            int row = m0 + rh * 64 + ty * 4 + i;
            #pragma unroll
            for (int ch = 0; ch < 2; ++ch) {
                int col = n0 + ch * 64 + tx * 4;
                float vv[4];
                #pragma unroll
                for (int j = 0; j < 4; ++j) vv[j] = acc[rh][ch][i][j];
                if (bias) {
                    #pragma unroll
                    for (int j = 0; j < 4; ++j) vv[j] += bias[col + j];
                }
                if (act) {
                    #pragma unroll
                    for (int j = 0; j < 4; ++j) vv[j] = gelu_f(vv[j]);
                }
                if (!transB) {
                    *(float4*)&out[(size_t)row * N + col] = make_float4(vv[0], vv[1], vv[2], vv[3]);
                } else {
                    #pragma unroll
                    for (int j = 0; j < 4; ++j)
                        if (col + j < N) out[(size_t)row * N + col + j] = vv[j];
                }
            }
        }
}

// ---------------------------------------------------------------- fused attention (online softmax)
// One block = (b,h) x 64-query tile. Quad of 4 lanes owns one query row.
// Q rows in registers (pre-scaled by 1/8 = sc^2, exact pow2). K/V staged 16 rows at a time in LDS.
__global__ __launch_bounds__(256)
void k_attn(const float* __restrict__ Q, const float* __restrict__ Kp,
            const float* __restrict__ Vp, float* __restrict__ Op,
            int Tq, int Tk, int causal) {
    __shared__ float Ks[16][68];
    __shared__ float Vs[16][68];
    const int bh = blockIdx.x, bb = bh / NHD, hh = bh % NHD;
    const int qs = blockIdx.y * 64;
    const int tid = threadIdx.x;
    const int qr = tid >> 2, cc = tid & 3;   // query row in tile, quad lane
    const int qg = qs + qr;                  // global query index
    const float* Qr = Q + ((size_t)(bb * Tq + qs + qr)) * ND + hh * NDH;
    const float* Kb = Kp + (size_t)bb * Tk * ND + hh * NDH;
    const float* Vb = Vp + (size_t)bb * Tk * ND + hh * NDH;

    float4 qreg[16];
    #pragma unroll
    for (int i = 0; i < 16; ++i) {
        float4 t = *(const float4*)&Qr[i * 4];
        t.x *= 0.125f; t.y *= 0.125f; t.z *= 0.125f; t.w *= 0.125f;
        qreg[i] = t;
    }
    float m = -INFINITY, lsum = 0.f;
    float Oa[16];
    #pragma unroll
    for (int i = 0; i < 16; ++i) Oa[i] = 0.f;

    const int nk = causal ? min(Tk, qs + 64) : Tk;
    const int kr = tid >> 4, kc4 = (tid & 15) * 4;   // staging map

    for (int kt = 0; kt < nk; kt += 16) {
        __syncthreads();   // previous tile's LDS reads done
        {
            int srow = kt + kr;
            float4 kv = make_float4(0, 0, 0, 0), vv = make_float4(0, 0, 0, 0);
            if (srow < Tk) {
                kv = *(const float4*)&Kb[(size_t)srow * ND + kc4];
                vv = *(const float4*)&Vb[(size_t)srow * ND + kc4];
            }
            *(float4*)&Ks[kr][kc4] = kv;
            *(float4*)&Vs[kr][kc4] = vv;
        }
        __syncthreads();

        // scores for 4 keys: cc*4 .. cc*4+3
        float s[4] = {0.f, 0.f, 0.f, 0.f};
        #pragma unroll
        for (int d4 = 0; d4 < 16; ++d4) {
            float4 q4 = qreg[d4];
            #pragma unroll
            for (int j = 0; j < 4; ++j) {
                float4 k4 = *(const float4*)&Ks[cc * 4 + j][d4 * 4];
                s[j] += q4.x * k4.x + q4.y * k4.y + q4.z * k4.z + q4.w * k4.w;
            }
        }
        #pragma unroll
        for (int j = 0; j < 4; ++j) {
            int kg = kt + cc * 4 + j;
            if (kg >= Tk || (causal && kg > qg)) s[j] = -INFINITY;
        }
        // quad max
        float mx = fmaxf(fmaxf(s[0], s[1]), fmaxf(s[2], s[3]));
        mx = fmaxf(mx, __shfl_xor(mx, 1, 4));
        mx = fmaxf(mx, __shfl_xor(mx, 2, 4));
        float mnew = fmaxf(m, mx);           // finite after first tile (key 0 always valid)
        float p[4], ps = 0.f;
        #pragma unroll
        for (int j = 0; j < 4; ++j) { p[j] = expf(s[j] - mnew); ps += p[j]; }
        ps += __shfl_xor(ps, 1, 4);
        ps += __shfl_xor(ps, 2, 4);
        float alpha = expf(m - mnew);        // exp(-inf - finite) = 0 on first tile
        lsum = lsum * alpha + ps;
        m = mnew;
        // broadcast all 16 p's within quad
        float pall[16];
        #pragma unroll
        for (int src = 0; src < 4; ++src)
            #pragma unroll
            for (int j = 0; j < 4; ++j)
                pall[src * 4 + j] = __shfl(p[j], src, 4);
        // O update: this lane owns dims cc*16 .. cc*16+15
        #pragma unroll
        for (int i = 0; i < 16; ++i) Oa[i] *= alpha;
        #pragma unroll
        for (int j2 = 0; j2 < 16; ++j2) {
            float pj = pall[j2];
            float vr[16];
            *(float4*)&vr[0]  = *(const float4*)&Vs[j2][cc * 16 + 0];
            *(float4*)&vr[4]  = *(const float4*)&Vs[j2][cc * 16 + 4];
            *(float4*)&vr[8]  = *(const float4*)&Vs[j2][cc * 16 + 8];
            *(float4*)&vr[12] = *(const float4*)&Vs[j2][cc * 16 + 12];
            #pragma unroll
            for (int i = 0; i < 16; ++i) Oa[i] = fmaf(pj, vr[i], Oa[i]);
        }
    }
    float inv = 1.f / lsum;
    float* Ob = Op + ((size_t)(bb * Tq + qs + qr)) * ND + hh * NDH + cc * 16;
    #pragma unroll
    for (int i4 = 0; i4 < 4; ++i4) {
        float4 o = make_float4(Oa[i4 * 4 + 0] * inv, Oa[i4 * 4 + 1] * inv,
                               Oa[i4 * 4 + 2] * inv, Oa[i4 * 4 + 3] * inv);
        *(float4*)&Ob[i4 * 4] = o;
    }
}

// ---------------------------------------------------------------- launch
extern "C" void kernel_launch(void* const* d_in, const int* in_sizes, int n_in,
                              void* d_out, int out_size, void* d_ws, size_t ws_size,
                              hipStream_t stream) {
    const int*   tokens  = (const int*)d_in[0];
    const float* kin     = (const float*)d_in[1];
    const float* vin     = (const float*)d_in[2];
    const float* tok_emb = (const float*)d_in[3];
    const float* pos_emb = (const float*)d_in[4];
    const float* Wq  = (const float*)d_in[5];
    const float* bq  = (const float*)d_in[6];
    const float* Wk  = (const float*)d_in[7];
    const float* Wv  = (const float*)d_in[8];
    const float* bv  = (const float*)d_in[9];
    const float* Wo  = (const float*)d_in[10];
    const float* bo  = (const float*)d_in[11];
    const float* ln1g = (const float*)d_in[12];
    const float* ln1b = (const float*)d_in[13];
    const float* cWq = (const float*)d_in[14];
    const float* cbq = (const float*)d_in[15];
    const float* cWo = (const float*)d_in[16];
    const float* cbo = (const float*)d_in[17];
    const float* ln2g = (const float*)d_in[18];
    const float* ln2b = (const float*)d_in[19];
    const float* W1  = (const float*)d_in[20];
    const float* b1  = (const float*)d_in[21];
    const float* W2  = (const float*)d_in[22];
    const float* b2  = (const float*)d_in[23];
    const float* ln3g = (const float*)d_in[24];
    const float* ln3b = (const float*)d_in[25];
    const float* lnfg = (const float*)d_in[26];
    const float* lnfb = (const float*)d_in[27];
    float* out = (float*)d_out;

    float* ws  = (float*)d_ws;
    float* x   = ws;                        // NR*ND
    float* h   = x  + (size_t)NR * ND;      // NR*ND
    float* qb  = h  + (size_t)NR * ND;      // NR*ND
    float* kb  = qb + (size_t)NR * ND;      // NR*ND
    float* vb  = kb + (size_t)NR * ND;      // NR*ND
    float* mid = vb + (size_t)NR * ND;      // NR*NDFF

    dim3 blk(256);
    dim3 g64(NR / 64, ND / 64);             // 28 x 12
    dim3 g128a(NR / 128, NDFF / 128);       // 14 x 24
    dim3 gattn(NB * NHD, NT / 64);          // 48 x 7
    dim3 glog(NR / 128, (NV + 127) / 128);  // 14 x 406

    k_embed<<<NR, blk, 0, stream>>>(tokens, tok_emb, pos_emb, x);

    for (int l = 0; l < NL; ++l) {
        size_t oDD = (size_t)l * ND * ND, oD = (size_t)l * ND;
        // --- self attention ---
        k_ln<<<NR, blk, 0, stream>>>(x, ln1g + oD, ln1b + oD, h);
        k_gemm64<<<g64, blk, 0, stream>>>(h, Wq + oDD, bq + oD, nullptr, qb, NR, ND, ND, 0);
        k_gemm64<<<g64, blk, 0, stream>>>(h, Wk + oDD, nullptr, nullptr, kb, NR, ND, ND, 0);
        k_gemm64<<<g64, blk, 0, stream>>>(h, Wv + oDD, bv + oD, nullptr, vb, NR, ND, ND, 0);
        k_attn<<<gattn, blk, 0, stream>>>(qb, kb, vb, h, NT, NT, 1);
        k_gemm64<<<g64, blk, 0, stream>>>(h, Wo + oDD, bo + oD, x, x, NR, ND, ND, 0);
        // --- cross attention (K/V precomputed, raw) ---
        k_ln<<<NR, blk, 0, stream>>>(x, ln2g + oD, ln2b + oD, h);
        k_gemm64<<<g64, blk, 0, stream>>>(h, cWq + oDD, cbq + oD, nullptr, qb, NR, ND, ND, 0);
        k_attn<<<gattn, blk, 0, stream>>>(qb, kin + (size_t)l * NB * NS * ND,
                                          vin + (size_t)l * NB * NS * ND, h, NT, NS, 0);
        k_gemm64<<<g64, blk, 0, stream>>>(h, cWo + oDD, cbo + oD, x, x, NR, ND, ND, 0);
        // --- MLP ---
        k_ln<<<NR, blk, 0, stream>>>(x, ln3g + oD, ln3b + oD, h);
        k_gemm128<<<g128a, blk, 0, stream>>>(h, W1 + (size_t)l * ND * NDFF, b1 + (size_t)l * NDFF,
                                             mid, NR, NDFF, ND, 1, 0);
        k_gemm64<<<g64, blk, 0, stream>>>(mid, W2 + (size_t)l * NDFF * ND, b2 + oD, x, x,
                                          NR, ND, NDFF, 0);
    }

    k_ln<<<NR, blk, 0, stream>>>(x, lnfg, lnfb, h);
    k_gemm128<<<glog, blk, 0, stream>>>(h, tok_emb, nullptr, out, NR, NV, ND, 0, 1);
}